// Round 18
// baseline (56.959 us; speedup 1.0000x reference)
//
#include <hip/hip_runtime.h>

#define NTOK 2048

typedef __attribute__((ext_vector_type(8))) short s8v;
typedef __attribute__((ext_vector_type(4))) float f32x4;

__device__ inline unsigned short f2bf(float f) {
  unsigned u = __builtin_bit_cast(unsigned, f);
  u += 0x7FFFu + ((u >> 16) & 1u);
  return (unsigned short)(u >> 16);
}

// ---- Kernel A: Wh = h@W, f1/f2 = Wh@a1/a2, WhT = bf16(Wh)^T, f2 min/max ----
__global__ __launch_bounds__(256) void gat_pre(
    const float* __restrict__ h, const float* __restrict__ W,
    const float* __restrict__ a, unsigned short* __restrict__ WhT,
    float* __restrict__ f1, float* __restrict__ f2,
    float* __restrict__ gmaxs, float* __restrict__ gmins) {
  __shared__ float wL[128 * 64];            // 32 KB
  __shared__ float hL[64 * 128];            // 32 KB
  __shared__ unsigned short tL[64 * 66];    // 8.25 KB [feat][tok] pad 66
  __shared__ float bmx[4], bmn[4];
  int t = threadIdx.x;
  {
    const float4* W4 = (const float4*)W;
    float4* wL4 = (float4*)wL;
#pragma unroll
    for (int k = 0; k < 8; ++k) wL4[t + 256 * k] = W4[t + 256 * k];
    const float4* h4 = (const float4*)(h + (size_t)blockIdx.x * 64 * 128);
    float4* hL4 = (float4*)hL;
#pragma unroll
    for (int k = 0; k < 8; ++k) hL4[t + 256 * k] = h4[t + 256 * k];
  }
  __syncthreads();
  int w = t >> 6, lane = t & 63;
  float acc[16];
#pragma unroll
  for (int r = 0; r < 16; ++r) acc[r] = 0.f;
  for (int kc = 0; kc < 128; kc += 32) {
    float wreg[32];
#pragma unroll
    for (int kk = 0; kk < 32; ++kk) wreg[kk] = wL[(kc + kk) * 64 + lane];
#pragma unroll
    for (int r = 0; r < 16; ++r) {
      const float* hrow = &hL[(w * 16 + r) * 128 + kc];
#pragma unroll
      for (int kk = 0; kk < 32; kk += 4) {
        float4 hv = *(const float4*)(hrow + kk);
        acc[r] += hv.x * wreg[kk] + hv.y * wreg[kk + 1] +
                  hv.z * wreg[kk + 2] + hv.w * wreg[kk + 3];
      }
    }
  }
  float a1 = a[lane], a2 = a[lane + 64];
  int row0 = blockIdx.x * 64 + w * 16;
  float wmx = -3.4e38f, wmn = 3.4e38f;
#pragma unroll
  for (int r = 0; r < 16; ++r) {
    float v1 = acc[r] * a1, v2 = acc[r] * a2;
#pragma unroll
    for (int s = 32; s; s >>= 1) {
      v1 += __shfl_xor(v1, s, 64);
      v2 += __shfl_xor(v2, s, 64);
    }
    if (lane == 0) { f1[row0 + r] = v1; f2[row0 + r] = v2; }
    wmx = fmaxf(wmx, v2);
    wmn = fminf(wmn, v2);
    tL[lane * 66 + w * 16 + r] = f2bf(acc[r]);
  }
  if (lane == 0) { bmx[w] = wmx; bmn[w] = wmn; }
  __syncthreads();
  int b = blockIdx.x >> 5;  // 32 blocks per batch
  if (t == 0) {
    float mx = fmaxf(fmaxf(bmx[0], bmx[1]), fmaxf(bmx[2], bmx[3]));
    float mn = fminf(fminf(bmn[0], bmn[1]), fminf(bmn[2], bmn[3]));
    gmaxs[b * 32 + (blockIdx.x & 31)] = mx;
    gmins[b * 32 + (blockIdx.x & 31)] = mn;
  }
  // WhT[b][feat][tok] write: 4 threads per feature, 64B-contiguous segments
  int tok0 = (blockIdx.x & 31) * 64;
  int f = t >> 2, sub = t & 3;
  const unsigned short* src = &tL[f * 66];
  unsigned short* dst = WhT + ((size_t)b * 64 + f) * NTOK + tok0;
  *(uint4*)(dst + sub * 8) = *(const uint4*)(src + sub * 8);
  *(uint4*)(dst + 32 + sub * 8) = *(const uint4*)(src + 32 + sub * 8);
}

// ---- Kernel B: R17 structure, stage folded UNDER the adj stream ----
// grid (16,8,4), 512 thr = 8 waves. Single asm region per wave:
// issue stream batch A(8) -> stage S(8)+f2(1) -> batch B(8); counted vmcnt
// retires A (pack d0, reissue A), then S (LDS stage write + lgkmcnt +
// RAW s_barrier -- stream loads stay in flight across it), then B (pack,
// reissue), etc. Stage latency + barrier hide entirely under the stream.
// Compute: per-wave LDS mask transpose, 16 chunks of {mask byte, f2L,
// swizzled ds_read_b128 B-frags, exp-in-fragment, 5 MFMAs}.
#define LOADX4(dst, va) \
  asm volatile("global_load_dwordx4 %0, %1, off" : "=v"(dst) : "v"(va))
#define LOADX1(dst, va) \
  asm volatile("global_load_dword %0, %1, off" : "=v"(dst) : "v"(va))
#define WAITV(n) \
  asm volatile("s_waitcnt vmcnt(" #n ")" ::: "memory"); \
  __builtin_amdgcn_sched_barrier(0)
#define PACK4(s0, s1, s2, s3, s4, s5, s6, s7, D)                               \
  {                                                                            \
    unsigned b0 = (unsigned)(s0.x > 0) | ((unsigned)(s0.y > 0) << 1) |         \
                  ((unsigned)(s0.z > 0) << 2) | ((unsigned)(s0.w > 0) << 3) |  \
                  ((unsigned)(s1.x > 0) << 4) | ((unsigned)(s1.y > 0) << 5) |  \
                  ((unsigned)(s1.z > 0) << 6) | ((unsigned)(s1.w > 0) << 7);   \
    unsigned b1 = (unsigned)(s2.x > 0) | ((unsigned)(s2.y > 0) << 1) |         \
                  ((unsigned)(s2.z > 0) << 2) | ((unsigned)(s2.w > 0) << 3) |  \
                  ((unsigned)(s3.x > 0) << 4) | ((unsigned)(s3.y > 0) << 5) |  \
                  ((unsigned)(s3.z > 0) << 6) | ((unsigned)(s3.w > 0) << 7);   \
    unsigned b2 = (unsigned)(s4.x > 0) | ((unsigned)(s4.y > 0) << 1) |         \
                  ((unsigned)(s4.z > 0) << 2) | ((unsigned)(s4.w > 0) << 3) |  \
                  ((unsigned)(s5.x > 0) << 4) | ((unsigned)(s5.y > 0) << 5) |  \
                  ((unsigned)(s5.z > 0) << 6) | ((unsigned)(s5.w > 0) << 7);   \
    unsigned b3 = (unsigned)(s6.x > 0) | ((unsigned)(s6.y > 0) << 1) |         \
                  ((unsigned)(s6.z > 0) << 2) | ((unsigned)(s6.w > 0) << 3) |  \
                  ((unsigned)(s7.x > 0) << 4) | ((unsigned)(s7.y > 0) << 5) |  \
                  ((unsigned)(s7.z > 0) << 6) | ((unsigned)(s7.w > 0) << 7);   \
    D = b0 | (b1 << 8) | (b2 << 16) | (b3 << 24);                              \
  }

__global__ __launch_bounds__(512, 4) void gat_main(
    const int* __restrict__ adj, const unsigned short* __restrict__ WhT,
    const float* __restrict__ f1, const float* __restrict__ f2,
    const float* __restrict__ gmaxs, const float* __restrict__ gmins,
    unsigned short* __restrict__ part, float* __restrict__ dsum) {
  __shared__ __align__(16) unsigned char wTile[65536];  // 64f x 512k bf16
  __shared__ float f2L[512];
  __shared__ __align__(16) unsigned char mT[8][1024];   // per-wave mask tile
  int t = threadIdx.x;
  int pt = blockIdx.x, b = blockIdx.y, ks = blockIdx.z;
  int w = t >> 6, lane = t & 63, l15 = lane & 15, lhi = lane >> 4;

  int rg = pt * 8 + w;
  int i0 = rg * 16;

  // ---- ms bound first: all loads consumed here -> vmcnt=0 at asm entry ----
  const float L2E = 1.44269504f;
  float f1s = f1[(size_t)b * NTOK + i0 + l15] * L2E;
  float gmx = -3.4e38f, gmn = 3.4e38f;
#pragma unroll
  for (int j = 0; j < 32; ++j) {
    gmx = fmaxf(gmx, gmaxs[b * 32 + j]);
    gmn = fminf(gmn, gmins[b * 32 + j]);
  }
  float mr = fmaxf(f1s * gmx, f1s * gmn);
  float ms = fmaxf(mr, 0.01f * mr);  // log2-scaled safe upper bound

  // ---- fused asm region: stream + stage + one counted-vmcnt barrier ----
  unsigned d0, d1, d2, d3;
  {
    const int* abase = adj + ((size_t)b * NTOK + i0) * NTOK + ks * 512;
    unsigned long long bp = (unsigned long long)abase + (unsigned)(lane * 32);
    // stage: wave w covers feature rows fr = it*8 + w, col = lane*16
    unsigned long long sb =
        (unsigned long long)(WhT + (size_t)b * 64 * NTOK) +
        (unsigned)(w * 4096 + ks * 1024 + lane * 16);
    unsigned long long fb =
        (unsigned long long)(f2 + (size_t)b * NTOK + ks * 512) + (unsigned)(t * 4);
    int4 A0, A1, A2, A3, A4, A5, A6, A7;
    int4 B0, B1, B2, B3, B4, B5, B6, B7;
    int4 S0, S1, S2, S3, S4, S5, S6, S7;
    int F0;
    __builtin_amdgcn_sched_barrier(0);
    // stream batch A: rows 0-3 of this wave's 16-row group
    LOADX4(A0, bp + 0ull);       LOADX4(A1, bp + 16ull);
    LOADX4(A2, bp + 8192ull);    LOADX4(A3, bp + 8208ull);
    LOADX4(A4, bp + 16384ull);   LOADX4(A5, bp + 16400ull);
    LOADX4(A6, bp + 24576ull);   LOADX4(A7, bp + 24592ull);
    // stage: 8 feature rows (stride 8 rows = 32 KB) + f2 dword
    LOADX4(S0, sb + 0ull);       LOADX4(S1, sb + 32768ull);
    LOADX4(S2, sb + 65536ull);   LOADX4(S3, sb + 98304ull);
    LOADX4(S4, sb + 131072ull);  LOADX4(S5, sb + 163840ull);
    LOADX4(S6, sb + 196608ull);  LOADX4(S7, sb + 229376ull);
    LOADX1(F0, fb);
    // stream batch B: rows 4-7
    LOADX4(B0, bp + 32768ull);   LOADX4(B1, bp + 32784ull);
    LOADX4(B2, bp + 40960ull);   LOADX4(B3, bp + 40976ull);
    LOADX4(B4, bp + 49152ull);   LOADX4(B5, bp + 49168ull);
    LOADX4(B6, bp + 57344ull);   LOADX4(B7, bp + 57360ull);
    WAITV(17);  // batch A retired (25 -> <=17)
    PACK4(A0, A1, A2, A3, A4, A5, A6, A7, d0);
    LOADX4(A0, bp + 65536ull);   LOADX4(A1, bp + 65552ull);  // rows 8-11
    LOADX4(A2, bp + 73728ull);   LOADX4(A3, bp + 73744ull);
    LOADX4(A4, bp + 81920ull);   LOADX4(A5, bp + 81936ull);
    LOADX4(A6, bp + 90112ull);   LOADX4(A7, bp + 90128ull);
    WAITV(16);  // stage + f2 retired; 16 stream loads still in flight
    {
      int col = lane * 16;
      int swz = w << 4;  // (fr&7)==w for all staged rows of this wave
      *(int4*)&wTile[(0 * 8 + w) * 1024 + (col ^ swz)] = S0;
      *(int4*)&wTile[(1 * 8 + w) * 1024 + (col ^ swz)] = S1;
      *(int4*)&wTile[(2 * 8 + w) * 1024 + (col ^ swz)] = S2;
      *(int4*)&wTile[(3 * 8 + w) * 1024 + (col ^ swz)] = S3;
      *(int4*)&wTile[(4 * 8 + w) * 1024 + (col ^ swz)] = S4;
      *(int4*)&wTile[(5 * 8 + w) * 1024 + (col ^ swz)] = S5;
      *(int4*)&wTile[(6 * 8 + w) * 1024 + (col ^ swz)] = S6;
      *(int4*)&wTile[(7 * 8 + w) * 1024 + (col ^ swz)] = S7;
      f2L[t] = __builtin_bit_cast(float, F0);
    }
    asm volatile("s_waitcnt lgkmcnt(0)" ::: "memory");
    __builtin_amdgcn_s_barrier();   // raw: stream loads stay in flight
    __builtin_amdgcn_sched_barrier(0);
    WAITV(8);  // batch B (rows 4-7) retired
    PACK4(B0, B1, B2, B3, B4, B5, B6, B7, d1);
    LOADX4(B0, bp + 98304ull);   LOADX4(B1, bp + 98320ull);  // rows 12-15
    LOADX4(B2, bp + 106496ull);  LOADX4(B3, bp + 106512ull);
    LOADX4(B4, bp + 114688ull);  LOADX4(B5, bp + 114704ull);
    LOADX4(B6, bp + 122880ull);  LOADX4(B7, bp + 122896ull);
    WAITV(8);  // rows 8-11 retired
    PACK4(A0, A1, A2, A3, A4, A5, A6, A7, d2);
    WAITV(0);  // rows 12-15 retired
    PACK4(B0, B1, B2, B3, B4, B5, B6, B7, d3);
    __builtin_amdgcn_sched_barrier(0);
  }

  // ---- per-wave LDS transpose (no barrier: same-wave write->read) ----
  {
    uint4 dd = {d0, d1, d2, d3};  // bytes: [colbyte=lane][row 0..15]
    *(uint4*)&mT[w][lane * 16] = dd;
  }

  const s8v bones = {0x3F80, 0x3F80, 0x3F80, 0x3F80, 0x3F80, 0x3F80, 0x3F80, 0x3F80};
  f32x4 ac0 = {0.f, 0.f, 0.f, 0.f}, ac1 = ac0, ac2 = ac0, ac3 = ac0, ac4 = ac0;
  int sw = (l15 & 7) << 4;

#pragma unroll
  for (int ch = 0; ch < 16; ++ch) {
    unsigned byte = mT[w][(ch * 4 + lhi) * 16 + l15];
    float4 v0 = *(const float4*)&f2L[ch * 32 + lhi * 8];
    float4 v1 = *(const float4*)&f2L[ch * 32 + lhi * 8 + 4];
    int kb = ch * 64 + lhi * 16;
    s8v bf0 = *(const s8v*)&wTile[l15 * 1024 + (kb ^ sw)];
    s8v bf1 = *(const s8v*)&wTile[(16 + l15) * 1024 + (kb ^ sw)];
    s8v bf2 = *(const s8v*)&wTile[(32 + l15) * 1024 + (kb ^ sw)];
    s8v bf3 = *(const s8v*)&wTile[(48 + l15) * 1024 + (kb ^ sw)];

    float sv[8] = {f1s * v0.x, f1s * v0.y, f1s * v0.z, f1s * v0.w,
                   f1s * v1.x, f1s * v1.y, f1s * v1.z, f1s * v1.w};
    s8v af;
#pragma unroll
    for (int q = 0; q < 8; ++q) {
      float sc = sv[q];
      float lk = fmaxf(sc, 0.01f * sc);
#if __has_builtin(__builtin_amdgcn_exp2f)
      float pe = __builtin_amdgcn_exp2f(lk - ms);
#else
      float pe = exp2f(lk - ms);
#endif
      float p = (byte & (1u << q)) ? pe : 0.f;
      unsigned uu = __builtin_bit_cast(unsigned, p) + 0x8000u;
      af[q] = (short)(uu >> 16);
    }
    ac0 = __builtin_amdgcn_mfma_f32_16x16x32_bf16(af, bf0, ac0, 0, 0, 0);
    ac1 = __builtin_amdgcn_mfma_f32_16x16x32_bf16(af, bf1, ac1, 0, 0, 0);
    ac2 = __builtin_amdgcn_mfma_f32_16x16x32_bf16(af, bf2, ac2, 0, 0, 0);
    ac3 = __builtin_amdgcn_mfma_f32_16x16x32_bf16(af, bf3, ac3, 0, 0, 0);
    ac4 = __builtin_amdgcn_mfma_f32_16x16x32_bf16(af, bones, ac4, 0, 0, 0);
  }

  // ---- write per-(rg,ks) partials: C rows = lhi*4+reg, cols = fb*16+l15 ----
  size_t pb = ((size_t)(b * 128 + rg)) * 4 + ks;
  unsigned short* pp = part + pb * 1024;
#pragma unroll
  for (int reg = 0; reg < 4; ++reg) {
    int row = lhi * 4 + reg;
    pp[row * 64 + l15] = f2bf(ac0[reg]);
    pp[row * 64 + 16 + l15] = f2bf(ac1[reg]);
    pp[row * 64 + 32 + l15] = f2bf(ac2[reg]);
    pp[row * 64 + 48 + l15] = f2bf(ac3[reg]);
    if (l15 == 0) dsum[pb * 16 + row] = ac4[reg];
  }
}

// ---- Kernel C: reduce 4 K-slices, normalize, ELU ----
__global__ __launch_bounds__(256) void gat_fin(
    const unsigned short* __restrict__ part, const float* __restrict__ dsum,
    float* __restrict__ out) {
  int gx = blockIdx.x, b = blockIdx.y, t = threadIdx.x;
  size_t g = (size_t)b * 128 + gx;
#pragma unroll
  for (int rep = 0; rep < 4; ++rep) {
    int idx = t + rep * 256;
    int mm = idx >> 6, f = idx & 63;
    float v = 0.f, dn = 0.f;
#pragma unroll
    for (int ks = 0; ks < 4; ++ks) {
      size_t pb = g * 4 + ks;
      unsigned us = part[pb * 1024 + mm * 64 + f];
      v += __builtin_bit_cast(float, us << 16);
      dn += dsum[pb * 16 + mm];
    }
    float rdn = dn > 0.f ? 1.0f / dn : 0.f;
    float hp = v * rdn;
    float o = hp > 0.f ? hp : expm1f(hp);
    out[((size_t)b * NTOK + gx * 16 + mm) * 64 + f] = o;
  }
}

extern "C" void kernel_launch(void* const* d_in, const int* in_sizes, int n_in,
                              void* d_out, int out_size, void* d_ws, size_t ws_size,
                              hipStream_t stream) {
  const float* h = (const float*)d_in[0];
  const int* adj = (const int*)d_in[1];
  const float* W = (const float*)d_in[2];
  const float* a = (const float*)d_in[3];
  float* out = (float*)d_out;

  char* ws = (char*)d_ws;
  unsigned short* WhT = (unsigned short*)ws;                // 2 MB
  float* f1 = (float*)(ws + 2 * 1024 * 1024);               // 64 KB
  float* f2 = f1 + 16384;                                   // 64 KB
  float* gmaxs = (float*)(f2 + 16384);                      // 1 KB
  float* gmins = gmaxs + 256;                               // 1 KB
  unsigned short* part = (unsigned short*)(ws + 3 * 1024 * 1024);  // 8 MB bf16
  float* dsum = (float*)(ws + 11 * 1024 * 1024);            // 256 KB

  gat_pre<<<256, 256, 0, stream>>>(h, W, a, WhT, f1, f2, gmaxs, gmins);
  gat_main<<<dim3(16, 8, 4), 512, 0, stream>>>(adj, WhT, f1, f2, gmaxs, gmins,
                                               part, dsum);
  gat_fin<<<dim3(128, 8), 256, 0, stream>>>(part, dsum, out);
}

// Round 19
// 53.368 us; speedup vs baseline: 1.0673x; 1.0673x over previous
//
#include <hip/hip_runtime.h>

#define NTOK 2048

typedef __attribute__((ext_vector_type(8))) short s8v;
typedef __attribute__((ext_vector_type(4))) float f32x4;

__device__ inline unsigned short f2bf(float f) {
  unsigned u = __builtin_bit_cast(unsigned, f);
  u += 0x7FFFu + ((u >> 16) & 1u);
  return (unsigned short)(u >> 16);
}

// ---- Kernel A: Wh = h@W, f1/f2 = Wh@a1/a2, WhT = bf16(Wh)^T, f2 min/max ----
__global__ __launch_bounds__(256) void gat_pre(
    const float* __restrict__ h, const float* __restrict__ W,
    const float* __restrict__ a, unsigned short* __restrict__ WhT,
    float* __restrict__ f1, float* __restrict__ f2,
    float* __restrict__ gmaxs, float* __restrict__ gmins) {
  __shared__ float wL[128 * 64];            // 32 KB
  __shared__ float hL[64 * 128];            // 32 KB
  __shared__ unsigned short tL[64 * 66];    // 8.25 KB [feat][tok] pad 66
  __shared__ float bmx[4], bmn[4];
  int t = threadIdx.x;
  {
    const float4* W4 = (const float4*)W;
    float4* wL4 = (float4*)wL;
#pragma unroll
    for (int k = 0; k < 8; ++k) wL4[t + 256 * k] = W4[t + 256 * k];
    const float4* h4 = (const float4*)(h + (size_t)blockIdx.x * 64 * 128);
    float4* hL4 = (float4*)hL;
#pragma unroll
    for (int k = 0; k < 8; ++k) hL4[t + 256 * k] = h4[t + 256 * k];
  }
  __syncthreads();
  int w = t >> 6, lane = t & 63;
  float acc[16];
#pragma unroll
  for (int r = 0; r < 16; ++r) acc[r] = 0.f;
  for (int kc = 0; kc < 128; kc += 32) {
    float wreg[32];
#pragma unroll
    for (int kk = 0; kk < 32; ++kk) wreg[kk] = wL[(kc + kk) * 64 + lane];
#pragma unroll
    for (int r = 0; r < 16; ++r) {
      const float* hrow = &hL[(w * 16 + r) * 128 + kc];
#pragma unroll
      for (int kk = 0; kk < 32; kk += 4) {
        float4 hv = *(const float4*)(hrow + kk);
        acc[r] += hv.x * wreg[kk] + hv.y * wreg[kk + 1] +
                  hv.z * wreg[kk + 2] + hv.w * wreg[kk + 3];
      }
    }
  }
  float a1 = a[lane], a2 = a[lane + 64];
  int row0 = blockIdx.x * 64 + w * 16;
  float wmx = -3.4e38f, wmn = 3.4e38f;
#pragma unroll
  for (int r = 0; r < 16; ++r) {
    float v1 = acc[r] * a1, v2 = acc[r] * a2;
#pragma unroll
    for (int s = 32; s; s >>= 1) {
      v1 += __shfl_xor(v1, s, 64);
      v2 += __shfl_xor(v2, s, 64);
    }
    if (lane == 0) { f1[row0 + r] = v1; f2[row0 + r] = v2; }
    wmx = fmaxf(wmx, v2);
    wmn = fminf(wmn, v2);
    tL[lane * 66 + w * 16 + r] = f2bf(acc[r]);
  }
  if (lane == 0) { bmx[w] = wmx; bmn[w] = wmn; }
  __syncthreads();
  int b = blockIdx.x >> 5;  // 32 blocks per batch
  if (t == 0) {
    float mx = fmaxf(fmaxf(bmx[0], bmx[1]), fmaxf(bmx[2], bmx[3]));
    float mn = fminf(fminf(bmn[0], bmn[1]), fminf(bmn[2], bmn[3]));
    gmaxs[b * 32 + (blockIdx.x & 31)] = mx;
    gmins[b * 32 + (blockIdx.x & 31)] = mn;
  }
  // WhT[b][feat][tok] write: 4 threads per feature, 64B-contiguous segments
  int tok0 = (blockIdx.x & 31) * 64;
  int f = t >> 2, sub = t & 3;
  const unsigned short* src = &tL[f * 66];
  unsigned short* dst = WhT + ((size_t)b * 64 + f) * NTOK + tok0;
  *(uint4*)(dst + sub * 8) = *(const uint4*)(src + sub * 8);
  *(uint4*)(dst + 32 + sub * 8) = *(const uint4*)(src + 32 + sub * 8);
}

// ---- Kernel B: chunk-major adj pipeline — load/compute interleaved ----
// grid (16,8,4), 512 thr = 8 waves. Stage wTile (flat fill) + f2L, ONE
// barrier. Then per wave, a 4-chunk-deep rolling pipeline over 16 chunks:
// chunk c's masks = 16 rows x 128B = 2 coalesced dwordx4 (lane=(r&7)*8+q
// covers 8 rows x 128B); WAITV(6) retires chunk c while 3 chunks stay in
// flight; pack 4-bit nibbles; reissue c+4; 4 __shfl build each MFMA
// lane's mask byte; exp-in-fragment + 5 MFMAs. No serial load phase.
#define LOADX4(dst, va) \
  asm volatile("global_load_dwordx4 %0, %1, off" : "=v"(dst) : "v"(va))
#define WAITV(n) \
  asm volatile("s_waitcnt vmcnt(" #n ")" ::: "memory"); \
  __builtin_amdgcn_sched_barrier(0)
#define NIB(X, N)                                                             \
  {                                                                           \
    int4 pp = X;                                                              \
    N = (unsigned)(pp.x > 0) | ((unsigned)(pp.y > 0) << 1) |                  \
        ((unsigned)(pp.z > 0) << 2) | ((unsigned)(pp.w > 0) << 3);            \
  }

__global__ __launch_bounds__(512, 4) void gat_main(
    const int* __restrict__ adj, const unsigned short* __restrict__ WhT,
    const float* __restrict__ f1, const float* __restrict__ f2,
    const float* __restrict__ gmaxs, const float* __restrict__ gmins,
    unsigned short* __restrict__ part, float* __restrict__ dsum) {
  __shared__ __align__(16) unsigned char wTile[65536];  // 64f x 512k bf16
  __shared__ float f2L[512];
  int t = threadIdx.x;
  int pt = blockIdx.x, b = blockIdx.y, ks = blockIdx.z;
  int w = t >> 6, lane = t & 63, l15 = lane & 15, lhi = lane >> 4;

  int rg = pt * 8 + w;
  int i0 = rg * 16;

  // ---- stage wTile (conflict-free flat fill) + f2L ----
  {
    const char* wsrc = (const char*)(WhT + (size_t)b * 64 * NTOK);
#pragma unroll
    for (int it = 0; it < 8; ++it) {
      int o = it * 8192 + t * 16;
      int fr = o >> 10;
      int col = o & 1023;
      uint4 d = *(const uint4*)(wsrc + (size_t)fr * 4096 + ks * 1024 + col);
      *(uint4*)&wTile[fr * 1024 + (col ^ ((fr & 7) << 4))] = d;
    }
    if (t < 128)
      ((float4*)f2L)[t] = ((const float4*)(f2 + (size_t)b * NTOK + ks * 512))[t];
  }

  // ---- ms bound (loads consumed before barrier) ----
  const float L2E = 1.44269504f;
  float f1s = f1[(size_t)b * NTOK + i0 + l15] * L2E;
  float gmx = -3.4e38f, gmn = 3.4e38f;
#pragma unroll
  for (int j = 0; j < 32; ++j) {
    gmx = fmaxf(gmx, gmaxs[b * 32 + j]);
    gmn = fminf(gmn, gmins[b * 32 + j]);
  }
  float mr = fmaxf(f1s * gmx, f1s * gmn);
  float ms = fmaxf(mr, 0.01f * mr);  // log2-scaled safe upper bound

  __syncthreads();  // wTile + f2L visible; vmcnt drained -> clean asm entry

  const s8v bones = {0x3F80, 0x3F80, 0x3F80, 0x3F80, 0x3F80, 0x3F80, 0x3F80, 0x3F80};
  f32x4 ac0 = {0.f, 0.f, 0.f, 0.f}, ac1 = ac0, ac2 = ac0, ac3 = ac0, ac4 = ac0;
  int sw = (l15 & 7) << 4;
  int psrc = ((l15 & 7) << 3) | (lhi << 1);  // producer lane for this byte
  int hsel = l15 >> 3;                       // 0: rows 0-7 (nA), 1: rows 8-15

  // chunk-major adj base: lane (r3=lane>>3, q=lane&7) covers row r3, 16B q
  unsigned long long abq =
      (unsigned long long)(adj + ((size_t)b * NTOK + i0) * NTOK) +
      (unsigned)(ks * 2048) + (unsigned)((lane >> 3) * 8192) +
      (unsigned)((lane & 7) * 16);

  int4 P0a, P0b, P1a, P1b, P2a, P2b, P3a, P3b;
  __builtin_amdgcn_sched_barrier(0);
  LOADX4(P0a, abq + 0ull);    LOADX4(P0b, abq + 65536ull);
  LOADX4(P1a, abq + 128ull);  LOADX4(P1b, abq + 65664ull);
  LOADX4(P2a, abq + 256ull);  LOADX4(P2b, abq + 65792ull);
  LOADX4(P3a, abq + 384ull);  LOADX4(P3b, abq + 65920ull);

#define COMPUTE_CHUNK(C, BYTE)                                                \
  {                                                                           \
    float4 v0 = *(const float4*)&f2L[(C) * 32 + lhi * 8];                     \
    float4 v1 = *(const float4*)&f2L[(C) * 32 + lhi * 8 + 4];                 \
    int kb = (C) * 64 + lhi * 16;                                             \
    s8v bf0 = *(const s8v*)&wTile[l15 * 1024 + (kb ^ sw)];                    \
    s8v bf1 = *(const s8v*)&wTile[(16 + l15) * 1024 + (kb ^ sw)];             \
    s8v bf2 = *(const s8v*)&wTile[(32 + l15) * 1024 + (kb ^ sw)];             \
    s8v bf3 = *(const s8v*)&wTile[(48 + l15) * 1024 + (kb ^ sw)];             \
    float sv[8] = {f1s * v0.x, f1s * v0.y, f1s * v0.z, f1s * v0.w,            \
                   f1s * v1.x, f1s * v1.y, f1s * v1.z, f1s * v1.w};           \
    s8v af;                                                                   \
    _Pragma("unroll") for (int q = 0; q < 8; ++q) {                           \
      float sc = sv[q];                                                       \
      float lk = fmaxf(sc, 0.01f * sc);                                       \
      float pe = exp2f(lk - ms);                                              \
      float p = ((BYTE) & (1u << q)) ? pe : 0.f;                              \
      unsigned uu = __builtin_bit_cast(unsigned, p) + 0x8000u;                \
      af[q] = (short)(uu >> 16);                                              \
    }                                                                         \
    ac0 = __builtin_amdgcn_mfma_f32_16x16x32_bf16(af, bf0, ac0, 0, 0, 0);     \
    ac1 = __builtin_amdgcn_mfma_f32_16x16x32_bf16(af, bf1, ac1, 0, 0, 0);     \
    ac2 = __builtin_amdgcn_mfma_f32_16x16x32_bf16(af, bf2, ac2, 0, 0, 0);     \
    ac3 = __builtin_amdgcn_mfma_f32_16x16x32_bf16(af, bf3, ac3, 0, 0, 0);     \
    ac4 = __builtin_amdgcn_mfma_f32_16x16x32_bf16(af, bones, ac4, 0, 0, 0);   \
  }

#define DOCHUNK(C, VM, Pa, Pb, DOISS)                                         \
  {                                                                           \
    WAITV(VM);                                                                \
    unsigned nA, nB;                                                          \
    NIB(Pa, nA);                                                              \
    NIB(Pb, nB);                                                              \
    if (DOISS) {                                                              \
      LOADX4(Pa, abq + (unsigned long long)((C) + 4) * 128ull);               \
      LOADX4(Pb, abq + (unsigned long long)((C) + 4) * 128ull + 65536ull);    \
    }                                                                         \
    unsigned a0 = (unsigned)__shfl((int)nA, psrc, 64);                        \
    unsigned a1 = (unsigned)__shfl((int)nA, psrc + 1, 64);                    \
    unsigned b0 = (unsigned)__shfl((int)nB, psrc, 64);                        \
    unsigned b1 = (unsigned)__shfl((int)nB, psrc + 1, 64);                    \
    unsigned byte = hsel ? (b0 | (b1 << 4)) : (a0 | (a1 << 4));               \
    COMPUTE_CHUNK(C, byte);                                                   \
  }

  DOCHUNK(0, 6, P0a, P0b, 1);
  DOCHUNK(1, 6, P1a, P1b, 1);
  DOCHUNK(2, 6, P2a, P2b, 1);
  DOCHUNK(3, 6, P3a, P3b, 1);
  DOCHUNK(4, 6, P0a, P0b, 1);
  DOCHUNK(5, 6, P1a, P1b, 1);
  DOCHUNK(6, 6, P2a, P2b, 1);
  DOCHUNK(7, 6, P3a, P3b, 1);
  DOCHUNK(8, 6, P0a, P0b, 1);
  DOCHUNK(9, 6, P1a, P1b, 1);
  DOCHUNK(10, 6, P2a, P2b, 1);
  DOCHUNK(11, 6, P3a, P3b, 1);
  DOCHUNK(12, 6, P0a, P0b, 0);
  DOCHUNK(13, 4, P1a, P1b, 0);
  DOCHUNK(14, 2, P2a, P2b, 0);
  DOCHUNK(15, 0, P3a, P3b, 0);
#undef DOCHUNK
#undef COMPUTE_CHUNK

  // ---- write per-(rg,ks) partials: C rows = lhi*4+reg, cols = fb*16+l15 ----
  size_t pb = ((size_t)(b * 128 + rg)) * 4 + ks;
  unsigned short* pp = part + pb * 1024;
#pragma unroll
  for (int reg = 0; reg < 4; ++reg) {
    int row = lhi * 4 + reg;
    pp[row * 64 + l15] = f2bf(ac0[reg]);
    pp[row * 64 + 16 + l15] = f2bf(ac1[reg]);
    pp[row * 64 + 32 + l15] = f2bf(ac2[reg]);
    pp[row * 64 + 48 + l15] = f2bf(ac3[reg]);
    if (l15 == 0) dsum[pb * 16 + row] = ac4[reg];
  }
}

// ---- Kernel C: reduce 4 K-slices, normalize, ELU ----
__global__ __launch_bounds__(256) void gat_fin(
    const unsigned short* __restrict__ part, const float* __restrict__ dsum,
    float* __restrict__ out) {
  int gx = blockIdx.x, b = blockIdx.y, t = threadIdx.x;
  size_t g = (size_t)b * 128 + gx;
#pragma unroll
  for (int rep = 0; rep < 4; ++rep) {
    int idx = t + rep * 256;
    int mm = idx >> 6, f = idx & 63;
    float v = 0.f, dn = 0.f;
#pragma unroll
    for (int ks = 0; ks < 4; ++ks) {
      size_t pb = g * 4 + ks;
      unsigned us = part[pb * 1024 + mm * 64 + f];
      v += __builtin_bit_cast(float, us << 16);
      dn += dsum[pb * 16 + mm];
    }
    float rdn = dn > 0.f ? 1.0f / dn : 0.f;
    float hp = v * rdn;
    float o = hp > 0.f ? hp : expm1f(hp);
    out[((size_t)b * NTOK + gx * 16 + mm) * 64 + f] = o;
  }
}

extern "C" void kernel_launch(void* const* d_in, const int* in_sizes, int n_in,
                              void* d_out, int out_size, void* d_ws, size_t ws_size,
                              hipStream_t stream) {
  const float* h = (const float*)d_in[0];
  const int* adj = (const int*)d_in[1];
  const float* W = (const float*)d_in[2];
  const float* a = (const float*)d_in[3];
  float* out = (float*)d_out;

  char* ws = (char*)d_ws;
  unsigned short* WhT = (unsigned short*)ws;                // 2 MB
  float* f1 = (float*)(ws + 2 * 1024 * 1024);               // 64 KB
  float* f2 = f1 + 16384;                                   // 64 KB
  float* gmaxs = (float*)(f2 + 16384);                      // 1 KB
  float* gmins = gmaxs + 256;                               // 1 KB
  unsigned short* part = (unsigned short*)(ws + 3 * 1024 * 1024);  // 8 MB bf16
  float* dsum = (float*)(ws + 11 * 1024 * 1024);            // 256 KB

  gat_pre<<<256, 256, 0, stream>>>(h, W, a, WhT, f1, f2, gmaxs, gmins);
  gat_main<<<dim3(16, 8, 4), 512, 0, stream>>>(adj, WhT, f1, f2, gmaxs, gmins,
                                               part, dsum);
  gat_fin<<<dim3(128, 8), 256, 0, stream>>>(part, dsum, out);
}